// Round 2
// baseline (136.399 us; speedup 1.0000x reference)
//
#include <hip/hip_runtime.h>

typedef __attribute__((ext_vector_type(4))) float f32x4;
typedef __attribute__((ext_vector_type(4))) int   i32x4;
typedef __attribute__((ext_vector_type(8))) int   i32x8;

#define DIM 256
#define D4  64    // float4 per row

// One wave per row. Rows [0,N): exact fp32 pos_sim -> posPart[row] + normalized
// pk -> fp8 e4m3 (plain byte-k order). Rows [N,N+M): normalized nv -> fp8.
// UNCHANGED (near its HBM floor).
__global__ __launch_bounds__(256) void normalize_kernel(
    const float4* __restrict__ pk, const float4* __restrict__ pv,
    const float4* __restrict__ nv, unsigned int* __restrict__ pkn,
    unsigned int* __restrict__ nvn, float* __restrict__ posPart, int N) {
  int row  = blockIdx.x * 4 + (threadIdx.x >> 6);
  int lane = threadIdx.x & 63;
  if (row < N) {
    float4 x = pk[row * D4 + lane];
    float4 y = pv[row * D4 + lane];
    float skk = x.x*x.x + x.y*x.y + x.z*x.z + x.w*x.w;
    float svv = y.x*y.x + y.y*y.y + y.z*y.z + y.w*y.w;
    float skv = x.x*y.x + x.y*y.y + x.z*y.z + x.w*y.w;
#pragma unroll
    for (int m = 32; m >= 1; m >>= 1) {
      skk += __shfl_xor(skk, m, 64);
      svv += __shfl_xor(svv, m, 64);
      skv += __shfl_xor(skv, m, 64);
    }
    float nk  = fmaxf(sqrtf(skk), 1e-8f);
    float nvv = fmaxf(sqrtf(svv), 1e-8f);
    if (lane == 0) posPart[row] = skv / (nk * nvv);
    float rk = 1.0f / nk;
    int w = __builtin_amdgcn_cvt_pk_fp8_f32(x.x * rk, x.y * rk, 0, false);
    w = __builtin_amdgcn_cvt_pk_fp8_f32(x.z * rk, x.w * rk, w, true);
    pkn[(size_t)row * 64 + lane] = (unsigned int)w;
  } else {
    int r2 = row - N;
    float4 x = nv[r2 * D4 + lane];
    float s = x.x*x.x + x.y*x.y + x.z*x.z + x.w*x.w;
#pragma unroll
    for (int m = 32; m >= 1; m >>= 1) s += __shfl_xor(s, m, 64);
    float rn = 1.0f / fmaxf(sqrtf(s), 1e-8f);
    int w = __builtin_amdgcn_cvt_pk_fp8_f32(x.x * rn, x.y * rn, 0, false);
    w = __builtin_amdgcn_cvt_pk_fp8_f32(x.z * rn, x.w * rn, w, true);
    nvn[(size_t)r2 * 64 + lane] = (unsigned int)w;
  }
}

// Fused fp8 GEMM (MX 16x16x128, unit scales = exact fp8) + exp(sim/2) + row-sum.
// R8: NO LDS. All fp8 operands (4MB total) are L2-resident (FETCH_SIZE ~0);
// R7's counters showed the staged version was phase-serialized (MfmaUtil 14%,
// Occ 17%, 2.1M LDS bank-conflict cycles): stage(1200cy) -> barrier drain ->
// LDS-read-bound compute (128 ds_read_b128 ~1540cy/CU > 1100cy MFMA) ran in
// lockstep across the 2 resident blocks. Guide common-mistake #7: don't stage
// what L2 already holds. The 16x16x128 fp8 fragment is K-contiguous per lane
// (row = l&15, bytes (l>>4)*32..+31 -- exactly what the old LDS reader
// decoded), so a direct 32B global load at row*256 + kb*128 + q*32 yields the
// bit-identical fragment: no barriers, no LDS, no swizzle, no bank conflicts.
// Waves in the 2x2 block pairwise share A/B panels -> L1 absorbs ~half the
// 536MB L2 traffic. Same accumulation order (kb0->kb1) -> bit-identical.
__global__ __launch_bounds__(256, 3) void gemm_lse_kernel(
    const unsigned char* __restrict__ gA, const unsigned char* __restrict__ gB,
    float* __restrict__ partial, int N) {
  const int tid  = threadIdx.x;
  const int lane = tid & 63;
  const int wv   = tid >> 6;
  const int wm   = wv >> 1, wn = wv & 1;
  const int l15  = lane & 15, q = lane >> 4;
  const int row0 = blockIdx.y * 128;
  const int col0 = blockIdx.x * 128;
  const float kLog2eHalf = 0.72134752044448170f;  // log2(e)/2
  const int kUnitScale = 0x7F7F7F7F;              // e8m0 127 = 2^0 per byte

  // per-lane fragment base: row = tile_row + l15, K-bytes (l>>4)*32
  const unsigned char* aB = gA + (size_t)(row0 + wm * 64 + l15) * 256 + q * 32;
  const unsigned char* bB = gB + (size_t)(col0 + wn * 64 + l15) * 256 + q * 32;

  f32x4 acc[4][4];
#pragma unroll
  for (int mi = 0; mi < 4; mi++)
#pragma unroll
    for (int ni = 0; ni < 4; ni++) acc[mi][ni] = (f32x4){0.f, 0.f, 0.f, 0.f};

#pragma unroll
  for (int kb = 0; kb < 2; kb++) {
    i32x8 af[4], bf[4];
#pragma unroll
    for (int mi = 0; mi < 4; mi++)
      af[mi] = *(const i32x8*)(aB + mi * 4096 + kb * 128);
#pragma unroll
    for (int ni = 0; ni < 4; ni++)
      bf[ni] = *(const i32x8*)(bB + ni * 4096 + kb * 128);
#pragma unroll
    for (int mi = 0; mi < 4; mi++)
#pragma unroll
      for (int ni = 0; ni < 4; ni++)
        acc[mi][ni] = __builtin_amdgcn_mfma_scale_f32_16x16x128_f8f6f4(
            af[mi], bf[ni], acc[mi][ni],
            0, 0, 0, kUnitScale, 0, kUnitScale);
  }

  // epilogue: exp2(sim*log2e/2); butterfly; one dense 256B store/wave, no atomics.
  float keep = 0.f;
#pragma unroll
  for (int mi = 0; mi < 4; mi++)
#pragma unroll
    for (int rr = 0; rr < 4; rr++) {
      float v = 0.f;
#pragma unroll
      for (int ni = 0; ni < 4; ni++)
        v += __builtin_amdgcn_exp2f(acc[mi][ni][rr] * kLog2eHalf);
      v += __shfl_xor(v, 1, 16);
      v += __shfl_xor(v, 2, 16);
      v += __shfl_xor(v, 4, 16);
      v += __shfl_xor(v, 8, 16);
      if (l15 == mi * 4 + rr) keep = v;
    }
  int lrow = (l15 >> 2) * 16 + q * 4 + (l15 & 3);
  partial[(size_t)(blockIdx.x * 2 + wn) * N + row0 + wm * 64 + lrow] = keep;
}

// out = mean(ln(sum_j partial[j][row])) - 0.5*mean(posPart). UNCHANGED.
__global__ __launch_bounds__(256) void finalize_kernel(
    const float* __restrict__ partial, const float* __restrict__ posPart,
    float* __restrict__ out, int N, int slabsPerGroup, float invN) {
  __shared__ float red[4][64];
  int t  = threadIdx.x;
  int rl = t & 63, g = t >> 6;
  int row = blockIdx.x * 64 + rl;
  const float* p = partial + (size_t)(g * slabsPerGroup) * N + row;
  float s = 0.f;
#pragma unroll 8
  for (int j = 0; j < slabsPerGroup; j++) s += p[(size_t)j * N];
  red[g][rl] = s;
  __syncthreads();
  if (t < 64) {
    float tot = red[0][rl] + red[1][rl] + red[2][rl] + red[3][rl];
    float v = __builtin_amdgcn_logf(tot) * 0.69314718055994531f
              - 0.5f * posPart[row];
#pragma unroll
    for (int m = 32; m >= 1; m >>= 1) v += __shfl_xor(v, m, 64);
    if (rl == 0) atomicAdd(out, v * invN);
  }
}

extern "C" void kernel_launch(void* const* d_in, const int* in_sizes, int n_in,
                              void* d_out, int out_size, void* d_ws, size_t ws_size,
                              hipStream_t stream) {
  const float* pk = (const float*)d_in[0];
  const float* pv = (const float*)d_in[1];
  const float* nv = (const float*)d_in[2];
  int N = in_sizes[0] / DIM;   // 8192
  int M = in_sizes[2] / DIM;   // 8192
  float* out = (float*)d_out;

  unsigned char* pkn = (unsigned char*)d_ws;                   // [N,256] fp8
  unsigned char* nvn = pkn + (size_t)N * DIM;                  // [M,256] fp8
  float* partial = (float*)(nvn + (size_t)M * DIM);            // [M/64][N] fp32
  float* posPart = partial + (size_t)(M / 64) * N;             // [N] fp32

  hipMemsetAsync(out, 0, sizeof(float), stream);

  normalize_kernel<<<(N + M) / 4, 256, 0, stream>>>(
      (const float4*)pk, (const float4*)pv, (const float4*)nv,
      (unsigned int*)pkn, (unsigned int*)nvn, posPart, N);

  gemm_lse_kernel<<<dim3(M / 128, N / 128), 256, 0, stream>>>(
      pkn, nvn, partial, N);

  finalize_kernel<<<N / 64, 256, 0, stream>>>(
      partial, posPart, out, N, (M / 64) / 4, 1.0f / (float)N);
}

// Round 3
// 106.785 us; speedup vs baseline: 1.2773x; 1.2773x over previous
//
#include <hip/hip_runtime.h>

typedef __attribute__((ext_vector_type(4))) float f32x4;
typedef __attribute__((ext_vector_type(4))) int   i32x4;
typedef __attribute__((ext_vector_type(8))) int   i32x8;

#define DIM 256
#define D4  64    // float4 per row

// async global->LDS, 16B per lane; LDS dest = wave-uniform base + lane*16.
#define GLD_LDS16(g, l) __builtin_amdgcn_global_load_lds(                      \
    (const __attribute__((address_space(1))) void*)(g),                        \
    (__attribute__((address_space(3))) void*)(l), 16, 0, 0)

// One wave per row. Rows [0,N): exact fp32 pos_sim -> posPart[row] + normalized
// pk -> fp8 e4m3 (plain byte-k order). Rows [N,N+M): normalized nv -> fp8.
// UNCHANGED (near its HBM floor).
__global__ __launch_bounds__(256) void normalize_kernel(
    const float4* __restrict__ pk, const float4* __restrict__ pv,
    const float4* __restrict__ nv, unsigned int* __restrict__ pkn,
    unsigned int* __restrict__ nvn, float* __restrict__ posPart, int N) {
  int row  = blockIdx.x * 4 + (threadIdx.x >> 6);
  int lane = threadIdx.x & 63;
  if (row < N) {
    float4 x = pk[row * D4 + lane];
    float4 y = pv[row * D4 + lane];
    float skk = x.x*x.x + x.y*x.y + x.z*x.z + x.w*x.w;
    float svv = y.x*y.x + y.y*y.y + y.z*y.z + y.w*y.w;
    float skv = x.x*y.x + x.y*y.y + x.z*y.z + x.w*y.w;
#pragma unroll
    for (int m = 32; m >= 1; m >>= 1) {
      skk += __shfl_xor(skk, m, 64);
      svv += __shfl_xor(svv, m, 64);
      skv += __shfl_xor(skv, m, 64);
    }
    float nk  = fmaxf(sqrtf(skk), 1e-8f);
    float nvv = fmaxf(sqrtf(svv), 1e-8f);
    if (lane == 0) posPart[row] = skv / (nk * nvv);
    float rk = 1.0f / nk;
    int w = __builtin_amdgcn_cvt_pk_fp8_f32(x.x * rk, x.y * rk, 0, false);
    w = __builtin_amdgcn_cvt_pk_fp8_f32(x.z * rk, x.w * rk, w, true);
    pkn[(size_t)row * 64 + lane] = (unsigned int)w;
  } else {
    int r2 = row - N;
    float4 x = nv[r2 * D4 + lane];
    float s = x.x*x.x + x.y*x.y + x.z*x.z + x.w*x.w;
#pragma unroll
    for (int m = 32; m >= 1; m >>= 1) s += __shfl_xor(s, m, 64);
    float rn = 1.0f / fmaxf(sqrtf(s), 1e-8f);
    int w = __builtin_amdgcn_cvt_pk_fp8_f32(x.x * rn, x.y * rn, 0, false);
    w = __builtin_amdgcn_cvt_pk_fp8_f32(x.z * rn, x.w * rn, w, true);
    nvn[(size_t)r2 * 64 + lane] = (unsigned int)w;
  }
}

// Fused fp8 GEMM (MX 16x16x128, unit scales = exact fp8) + exp(sim/2) + row-sum.
// R9: 256x256 tile, 8 waves (2 row-halves x 4 col-quarters), full K=256 in
// LDS (A 64KB + B 64KB = 128KB, 1 block/CU, same budget as the proven m201
// 8-phase template). Why: R8 showed no-LDS is L2-BW/latency-bound (4x L2
// traffic, MfmaUtil 10%); R7 showed the 128^2 staged tile has too little
// compute per staged byte (32 MFMA/wave vs ~650cy stage + ~1500cy LDS reads,
// lockstep x2 blocks). 256^2 doubles MFMA per LDS byte: 64 MFMA/wave
// (~4400cy/SIMD) vs ~1150cy LDS reads -> reads hide under MFMA with
// 2 waves/SIMD; one 128KB stage amortized over 4x the compute.
// Staging idiom, XOR swizzle, fragment decode, kb0->kb1 accumulation order
// all UNCHANGED from R7 -> bit-identical numerics. Grid (M/256, N/256).
__global__ __launch_bounds__(512, 2) void gemm_lse_kernel(
    const unsigned char* __restrict__ gA, const unsigned char* __restrict__ gB,
    float* __restrict__ partial, int N) {
  __shared__ unsigned char As[65536];  // [2 kb][256 rows][8 chunks 16B, XOR-swz]
  __shared__ unsigned char Bs[65536];

  const int tid  = threadIdx.x;
  const int lane = tid & 63;
  const int wv   = tid >> 6;      // 0..7
  const int wm   = wv >> 2;       // 0..1 : 128-row half
  const int wn   = wv & 3;        // 0..3 : 64-col quarter
  const int l15  = lane & 15, q = lane >> 4;
  const int row0 = blockIdx.y * 256;
  const int col0 = blockIdx.x * 256;
  const float kLog2eHalf = 0.72134752044448170f;  // log2(e)/2
  const int kUnitScale = 0x7F7F7F7F;              // e8m0 127 = 2^0 per byte

  f32x4 acc[8][4];
#pragma unroll
  for (int mi = 0; mi < 8; mi++)
#pragma unroll
    for (int ni = 0; ni < 4; ni++) acc[mi][ni] = (f32x4){0.f, 0.f, 0.f, 0.f};

  // Single full-K stage: 16 async 16B loads per thread (2048 chunks per
  // matrix per kb-half, 512 threads -> 4 iters), then ONE barrier.
#pragma unroll
  for (int kb = 0; kb < 2; kb++)
#pragma unroll
    for (int i = 0; i < 4; i++) {
      int c  = i * 512 + tid;            // chunk index within this K-half
      int r  = c >> 3;                   // row (8 chunks of 16B per half-row)
      int sc = ((c & 7) ^ (r & 7)) << 4; // pre-swizzled global source col
      GLD_LDS16(gA + (size_t)(row0 + r) * 256 + kb * 128 + sc,
                As + kb * 32768 + c * 16);
      GLD_LDS16(gB + (size_t)(col0 + r) * 256 + kb * 128 + sc,
                Bs + kb * 32768 + c * 16);
    }
  __syncthreads();   // sole barrier

#pragma unroll
  for (int kb = 0; kb < 2; kb++) {
    const int kbo = kb * 32768;
    i32x8 bf[4];
#pragma unroll
    for (int ni = 0; ni < 4; ni++) {
      int r  = wn * 64 + ni * 16 + l15;
      int c0 = (q * 2)     ^ (r & 7);
      int c1 = (q * 2 + 1) ^ (r & 7);
      i32x4 lo = *(const i32x4*)(Bs + kbo + r * 128 + c0 * 16);
      i32x4 hi = *(const i32x4*)(Bs + kbo + r * 128 + c1 * 16);
      bf[ni] = (i32x8){lo.x, lo.y, lo.z, lo.w, hi.x, hi.y, hi.z, hi.w};
    }
#pragma unroll
    for (int mi = 0; mi < 8; mi++) {
      int r  = wm * 128 + mi * 16 + l15;
      int c0 = (q * 2)     ^ (r & 7);
      int c1 = (q * 2 + 1) ^ (r & 7);
      i32x4 lo = *(const i32x4*)(As + kbo + r * 128 + c0 * 16);
      i32x4 hi = *(const i32x4*)(As + kbo + r * 128 + c1 * 16);
      i32x8 af = (i32x8){lo.x, lo.y, lo.z, lo.w, hi.x, hi.y, hi.z, hi.w};
#pragma unroll
      for (int ni = 0; ni < 4; ni++)
        acc[mi][ni] = __builtin_amdgcn_mfma_scale_f32_16x16x128_f8f6f4(
            af, bf[ni], acc[mi][ni],
            0, 0, 0, kUnitScale, 0, kUnitScale);
    }
  }

  // epilogue: exp2(sim*log2e/2); butterfly over 16 cols x 4 ni-tiles = the
  // wave's full 64-col strip; each lane keeps 2 of its wave's 128 rows.
  float keep0 = 0.f, keep1 = 0.f;
#pragma unroll
  for (int mi = 0; mi < 8; mi++)
#pragma unroll
    for (int rr = 0; rr < 4; rr++) {
      float v = 0.f;
#pragma unroll
      for (int ni = 0; ni < 4; ni++)
        v += __builtin_amdgcn_exp2f(acc[mi][ni][rr] * kLog2eHalf);
      v += __shfl_xor(v, 1, 16);
      v += __shfl_xor(v, 2, 16);
      v += __shfl_xor(v, 4, 16);
      v += __shfl_xor(v, 8, 16);
      if (l15 == (mi & 3) * 4 + rr) { if (mi < 4) keep0 = v; else keep1 = v; }
    }
  // lane (q,l15) holds rows {base, 64+base} of its wave's 128-row strip
  int base = (l15 >> 2) * 16 + q * 4 + (l15 & 3);
  size_t slab = (size_t)(blockIdx.x * 4 + wn);   // 64-col slab, 0..127
  partial[slab * N + row0 + wm * 128 + base]      = keep0;
  partial[slab * N + row0 + wm * 128 + 64 + base] = keep1;
}

// out = mean(ln(sum_j partial[j][row])) - 0.5*mean(posPart). UNCHANGED
// (partial is still [M/64=128][N]).
__global__ __launch_bounds__(256) void finalize_kernel(
    const float* __restrict__ partial, const float* __restrict__ posPart,
    float* __restrict__ out, int N, int slabsPerGroup, float invN) {
  __shared__ float red[4][64];
  int t  = threadIdx.x;
  int rl = t & 63, g = t >> 6;
  int row = blockIdx.x * 64 + rl;
  const float* p = partial + (size_t)(g * slabsPerGroup) * N + row;
  float s = 0.f;
#pragma unroll 8
  for (int j = 0; j < slabsPerGroup; j++) s += p[(size_t)j * N];
  red[g][rl] = s;
  __syncthreads();
  if (t < 64) {
    float tot = red[0][rl] + red[1][rl] + red[2][rl] + red[3][rl];
    float v = __builtin_amdgcn_logf(tot) * 0.69314718055994531f
              - 0.5f * posPart[row];
#pragma unroll
    for (int m = 32; m >= 1; m >>= 1) v += __shfl_xor(v, m, 64);
    if (rl == 0) atomicAdd(out, v * invN);
  }
}

extern "C" void kernel_launch(void* const* d_in, const int* in_sizes, int n_in,
                              void* d_out, int out_size, void* d_ws, size_t ws_size,
                              hipStream_t stream) {
  const float* pk = (const float*)d_in[0];
  const float* pv = (const float*)d_in[1];
  const float* nv = (const float*)d_in[2];
  int N = in_sizes[0] / DIM;   // 8192
  int M = in_sizes[2] / DIM;   // 8192
  float* out = (float*)d_out;

  unsigned char* pkn = (unsigned char*)d_ws;                   // [N,256] fp8
  unsigned char* nvn = pkn + (size_t)N * DIM;                  // [M,256] fp8
  float* partial = (float*)(nvn + (size_t)M * DIM);            // [M/64][N] fp32
  float* posPart = partial + (size_t)(M / 64) * N;             // [N] fp32

  hipMemsetAsync(out, 0, sizeof(float), stream);

  normalize_kernel<<<(N + M) / 4, 256, 0, stream>>>(
      (const float4*)pk, (const float4*)pv, (const float4*)nv,
      (unsigned int*)pkn, (unsigned int*)nvn, posPart, N);

  gemm_lse_kernel<<<dim3(M / 256, N / 256), 512, 0, stream>>>(
      pkn, nvn, partial, N);

  finalize_kernel<<<N / 64, 256, 0, stream>>>(
      partial, posPart, out, N, (M / 64) / 4, 1.0f / (float)N);
}

// Round 4
// 103.814 us; speedup vs baseline: 1.3139x; 1.0286x over previous
//
#include <hip/hip_runtime.h>

typedef __attribute__((ext_vector_type(4))) float f32x4;
typedef __attribute__((ext_vector_type(4))) int   i32x4;
typedef __attribute__((ext_vector_type(8))) int   i32x8;

#define DIM 256
#define D4  64    // float4 per row

// async global->LDS, 16B per lane; LDS dest = wave-uniform base + lane*16.
#define GLD_LDS16(g, l) __builtin_amdgcn_global_load_lds(                      \
    (const __attribute__((address_space(1))) void*)(g),                        \
    (__attribute__((address_space(3))) void*)(l), 16, 0, 0)

// One wave per row. Rows [0,N): exact fp32 pos_sim -> posPart[row] + normalized
// pk -> fp8 e4m3 (plain byte-k order). Rows [N,N+M): normalized nv -> fp8.
// UNCHANGED (near its HBM floor).
__global__ __launch_bounds__(256) void normalize_kernel(
    const float4* __restrict__ pk, const float4* __restrict__ pv,
    const float4* __restrict__ nv, unsigned int* __restrict__ pkn,
    unsigned int* __restrict__ nvn, float* __restrict__ posPart, int N) {
  int row  = blockIdx.x * 4 + (threadIdx.x >> 6);
  int lane = threadIdx.x & 63;
  if (row < N) {
    float4 x = pk[row * D4 + lane];
    float4 y = pv[row * D4 + lane];
    float skk = x.x*x.x + x.y*x.y + x.z*x.z + x.w*x.w;
    float svv = y.x*y.x + y.y*y.y + y.z*y.z + y.w*y.w;
    float skv = x.x*y.x + x.y*y.y + x.z*y.z + x.w*y.w;
#pragma unroll
    for (int m = 32; m >= 1; m >>= 1) {
      skk += __shfl_xor(skk, m, 64);
      svv += __shfl_xor(svv, m, 64);
      skv += __shfl_xor(skv, m, 64);
    }
    float nk  = fmaxf(sqrtf(skk), 1e-8f);
    float nvv = fmaxf(sqrtf(svv), 1e-8f);
    if (lane == 0) posPart[row] = skv / (nk * nvv);
    float rk = 1.0f / nk;
    int w = __builtin_amdgcn_cvt_pk_fp8_f32(x.x * rk, x.y * rk, 0, false);
    w = __builtin_amdgcn_cvt_pk_fp8_f32(x.z * rk, x.w * rk, w, true);
    pkn[(size_t)row * 64 + lane] = (unsigned int)w;
  } else {
    int r2 = row - N;
    float4 x = nv[r2 * D4 + lane];
    float s = x.x*x.x + x.y*x.y + x.z*x.z + x.w*x.w;
#pragma unroll
    for (int m = 32; m >= 1; m >>= 1) s += __shfl_xor(s, m, 64);
    float rn = 1.0f / fmaxf(sqrtf(s), 1e-8f);
    int w = __builtin_amdgcn_cvt_pk_fp8_f32(x.x * rn, x.y * rn, 0, false);
    w = __builtin_amdgcn_cvt_pk_fp8_f32(x.z * rn, x.w * rn, w, true);
    nvn[(size_t)r2 * 64 + lane] = (unsigned int)w;
  }
}

// Fused fp8 GEMM (MX 16x16x128, unit scales = exact fp8) + exp(sim/2) + row-sum.
// R10: operand-swapped MFMA (T12 trick). R3's ~39us gemm decomposed as
// ~4.4k cy MFMA + ~4.6k ds_read + ~2.5k stage + ~6k cy EPILOGUE LDS-pipe:
// the old butterfly did 128 ds_bpermute/wave (reduction axis = D-cols,
// spread across 16 lanes; R1's VALUBusy=32% and 2.1M "bank conflict" cycles
// were these bpermutes). Swapping acc = mfma(bf, af) transposes D so lane
// l15 holds a pk-ROW and its 4 regs span nv-cols: row-sum = sum_ni sum_rr
// IN-REGISTER + 2 cross-q shuffles per mi -> 16 shuffles/wave (8x fewer).
// Dot products bit-identical (only 64-col sum order changes: butterfly ->
// sequential+2-level). Also: split-barrier stage with counted vmcnt(8)
// (kb1's 64KB hides under kb0 compute, T4) and setprio around MFMA (T5).
// 256x256 tile, 8 waves (2 row-halves x 4 col-quarters), full K=256 in LDS.
__global__ __launch_bounds__(512, 2) void gemm_lse_kernel(
    const unsigned char* __restrict__ gA, const unsigned char* __restrict__ gB,
    float* __restrict__ partial, int N) {
  __shared__ unsigned char As[65536];  // [2 kb][256 rows][8 chunks 16B, XOR-swz]
  __shared__ unsigned char Bs[65536];

  const int tid  = threadIdx.x;
  const int lane = tid & 63;
  const int wv   = tid >> 6;      // 0..7
  const int wm   = wv >> 2;       // 0..1 : 128-row half
  const int wn   = wv & 3;        // 0..3 : 64-col quarter
  const int l15  = lane & 15, q = lane >> 4;
  const int row0 = blockIdx.y * 256;
  const int col0 = blockIdx.x * 256;
  const float kLog2eHalf = 0.72134752044448170f;  // log2(e)/2
  const int kUnitScale = 0x7F7F7F7F;              // e8m0 127 = 2^0 per byte

  f32x4 acc[8][4];
#pragma unroll
  for (int mi = 0; mi < 8; mi++)
#pragma unroll
    for (int ni = 0; ni < 4; ni++) acc[mi][ni] = (f32x4){0.f, 0.f, 0.f, 0.f};

  // Stage full K: 16 async 16B loads/thread, kb0's 8 first, then kb1's 8.
#pragma unroll
  for (int kb = 0; kb < 2; kb++)
#pragma unroll
    for (int i = 0; i < 4; i++) {
      int c  = i * 512 + tid;            // chunk index within this K-half
      int r  = c >> 3;                   // row (8 chunks of 16B per half-row)
      int sc = ((c & 7) ^ (r & 7)) << 4; // pre-swizzled global source col
      GLD_LDS16(gA + (size_t)(row0 + r) * 256 + kb * 128 + sc,
                As + kb * 32768 + c * 16);
      GLD_LDS16(gB + (size_t)(col0 + r) * 256 + kb * 128 + sc,
                Bs + kb * 32768 + c * 16);
    }

#pragma unroll
  for (int kb = 0; kb < 2; kb++) {
    // kb0: wait only for own first 8 loads (kb0 data), kb1 stays in flight
    // and lands during kb0 compute. kb1: drain all. Barrier joins waves; each
    // thread's own-loads-retired + barrier => all staged data LDS-visible.
    if (kb == 0) asm volatile("s_waitcnt vmcnt(8)\n\ts_barrier" ::: "memory");
    else         asm volatile("s_waitcnt vmcnt(0)\n\ts_barrier" ::: "memory");

    const int kbo = kb * 32768;
    i32x8 bf[4];
#pragma unroll
    for (int ni = 0; ni < 4; ni++) {
      int r  = wn * 64 + ni * 16 + l15;
      int c0 = (q * 2)     ^ (r & 7);
      int c1 = (q * 2 + 1) ^ (r & 7);
      i32x4 lo = *(const i32x4*)(Bs + kbo + r * 128 + c0 * 16);
      i32x4 hi = *(const i32x4*)(Bs + kbo + r * 128 + c1 * 16);
      bf[ni] = (i32x8){lo.x, lo.y, lo.z, lo.w, hi.x, hi.y, hi.z, hi.w};
    }
#pragma unroll
    for (int mi = 0; mi < 8; mi++) {
      int r  = wm * 128 + mi * 16 + l15;
      int c0 = (q * 2)     ^ (r & 7);
      int c1 = (q * 2 + 1) ^ (r & 7);
      i32x4 lo = *(const i32x4*)(As + kbo + r * 128 + c0 * 16);
      i32x4 hi = *(const i32x4*)(As + kbo + r * 128 + c1 * 16);
      i32x8 af = (i32x8){lo.x, lo.y, lo.z, lo.w, hi.x, hi.y, hi.z, hi.w};
      __builtin_amdgcn_s_setprio(1);
#pragma unroll
      for (int ni = 0; ni < 4; ni++)
        acc[mi][ni] = __builtin_amdgcn_mfma_scale_f32_16x16x128_f8f6f4(
            bf[ni], af, acc[mi][ni],        // SWAPPED: D[col][row]
            0, 0, 0, kUnitScale, 0, kUnitScale);
      __builtin_amdgcn_s_setprio(0);
    }
  }

  // epilogue: lane (q,l15) holds, for tile (mi,ni), D'[q*4+rr][l15] =
  // sim(pk row mi*16+l15, nv col ni*16+q*4+rr). Row-sum over the wave's 64
  // cols = sum_ni sum_rr in-register + 2 cross-q shuffles. No butterfly.
  float s[8];
#pragma unroll
  for (int mi = 0; mi < 8; mi++) {
    float v = 0.f;
#pragma unroll
    for (int ni = 0; ni < 4; ni++)
#pragma unroll
      for (int rr = 0; rr < 4; rr++)
        v += __builtin_amdgcn_exp2f(acc[mi][ni][rr] * kLog2eHalf);
    v += __shfl_xor(v, 16, 64);
    v += __shfl_xor(v, 32, 64);
    s[mi] = v;
  }
  // lane (q,l15) stores rows q*16+l15 (mi=q) and +64 (mi=q+4): one fully
  // coalesced 256B store per wave per half.
  float o0 = q == 0 ? s[0] : q == 1 ? s[1] : q == 2 ? s[2] : s[3];
  float o1 = q == 0 ? s[4] : q == 1 ? s[5] : q == 2 ? s[6] : s[7];
  size_t slab = (size_t)(blockIdx.x * 4 + wn);   // 64-col slab, 0..127
  int r0 = row0 + wm * 128 + q * 16 + l15;
  partial[slab * N + r0]      = o0;
  partial[slab * N + r0 + 64] = o1;
}

// out = mean(ln(sum_j partial[j][row])) - 0.5*mean(posPart). UNCHANGED
// (partial is still [M/64=128][N]).
__global__ __launch_bounds__(256) void finalize_kernel(
    const float* __restrict__ partial, const float* __restrict__ posPart,
    float* __restrict__ out, int N, int slabsPerGroup, float invN) {
  __shared__ float red[4][64];
  int t  = threadIdx.x;
  int rl = t & 63, g = t >> 6;
  int row = blockIdx.x * 64 + rl;
  const float* p = partial + (size_t)(g * slabsPerGroup) * N + row;
  float s = 0.f;
#pragma unroll 8
  for (int j = 0; j < slabsPerGroup; j++) s += p[(size_t)j * N];
  red[g][rl] = s;
  __syncthreads();
  if (t < 64) {
    float tot = red[0][rl] + red[1][rl] + red[2][rl] + red[3][rl];
    float v = __builtin_amdgcn_logf(tot) * 0.69314718055994531f
              - 0.5f * posPart[row];
#pragma unroll
    for (int m = 32; m >= 1; m >>= 1) v += __shfl_xor(v, m, 64);
    if (rl == 0) atomicAdd(out, v * invN);
  }
}

extern "C" void kernel_launch(void* const* d_in, const int* in_sizes, int n_in,
                              void* d_out, int out_size, void* d_ws, size_t ws_size,
                              hipStream_t stream) {
  const float* pk = (const float*)d_in[0];
  const float* pv = (const float*)d_in[1];
  const float* nv = (const float*)d_in[2];
  int N = in_sizes[0] / DIM;   // 8192
  int M = in_sizes[2] / DIM;   // 8192
  float* out = (float*)d_out;

  unsigned char* pkn = (unsigned char*)d_ws;                   // [N,256] fp8
  unsigned char* nvn = pkn + (size_t)N * DIM;                  // [M,256] fp8
  float* partial = (float*)(nvn + (size_t)M * DIM);            // [M/64][N] fp32
  float* posPart = partial + (size_t)(M / 64) * N;             // [N] fp32

  hipMemsetAsync(out, 0, sizeof(float), stream);

  normalize_kernel<<<(N + M) / 4, 256, 0, stream>>>(
      (const float4*)pk, (const float4*)pv, (const float4*)nv,
      (unsigned int*)pkn, (unsigned int*)nvn, posPart, N);

  gemm_lse_kernel<<<dim3(M / 256, N / 256), 512, 0, stream>>>(
      pkn, nvn, partial, N);

  finalize_kernel<<<N / 64, 256, 0, stream>>>(
      partial, posPart, out, N, (M / 64) / 4, 1.0f / (float)N);
}

// Round 5
// 101.045 us; speedup vs baseline: 1.3499x; 1.0274x over previous
//
#include <hip/hip_runtime.h>

typedef __attribute__((ext_vector_type(4))) float f32x4;
typedef __attribute__((ext_vector_type(4))) int   i32x4;
typedef __attribute__((ext_vector_type(8))) int   i32x8;

#define DIM 256
#define D4  64    // float4 per row

// async global->LDS, 16B per lane; LDS dest = wave-uniform base + lane*16.
#define GLD_LDS16(g, l) __builtin_amdgcn_global_load_lds(                      \
    (const __attribute__((address_space(1))) void*)(g),                        \
    (__attribute__((address_space(3))) void*)(l), 16, 0, 0)

// One wave per row. Rows [0,N): exact fp32 pos_sim -> posPart[row] + normalized
// pk -> fp8 e4m3 (plain byte-k order). Rows [N,N+M): normalized nv -> fp8.
// UNCHANGED (near its HBM floor).
__global__ __launch_bounds__(256) void normalize_kernel(
    const float4* __restrict__ pk, const float4* __restrict__ pv,
    const float4* __restrict__ nv, unsigned int* __restrict__ pkn,
    unsigned int* __restrict__ nvn, float* __restrict__ posPart, int N) {
  int row  = blockIdx.x * 4 + (threadIdx.x >> 6);
  int lane = threadIdx.x & 63;
  if (row < N) {
    float4 x = pk[row * D4 + lane];
    float4 y = pv[row * D4 + lane];
    float skk = x.x*x.x + x.y*x.y + x.z*x.z + x.w*x.w;
    float svv = y.x*y.x + y.y*y.y + y.z*y.z + y.w*y.w;
    float skv = x.x*y.x + x.y*y.y + x.z*y.z + x.w*y.w;
#pragma unroll
    for (int m = 32; m >= 1; m >>= 1) {
      skk += __shfl_xor(skk, m, 64);
      svv += __shfl_xor(svv, m, 64);
      skv += __shfl_xor(skv, m, 64);
    }
    float nk  = fmaxf(sqrtf(skk), 1e-8f);
    float nvv = fmaxf(sqrtf(svv), 1e-8f);
    if (lane == 0) posPart[row] = skv / (nk * nvv);
    float rk = 1.0f / nk;
    int w = __builtin_amdgcn_cvt_pk_fp8_f32(x.x * rk, x.y * rk, 0, false);
    w = __builtin_amdgcn_cvt_pk_fp8_f32(x.z * rk, x.w * rk, w, true);
    pkn[(size_t)row * 64 + lane] = (unsigned int)w;
  } else {
    int r2 = row - N;
    float4 x = nv[r2 * D4 + lane];
    float s = x.x*x.x + x.y*x.y + x.z*x.z + x.w*x.w;
#pragma unroll
    for (int m = 32; m >= 1; m >>= 1) s += __shfl_xor(s, m, 64);
    float rn = 1.0f / fmaxf(sqrtf(s), 1e-8f);
    int w = __builtin_amdgcn_cvt_pk_fp8_f32(x.x * rn, x.y * rn, 0, false);
    w = __builtin_amdgcn_cvt_pk_fp8_f32(x.z * rn, x.w * rn, w, true);
    nvn[(size_t)r2 * 64 + lane] = (unsigned int)w;
  }
}

// Fused fp8 GEMM (MX 16x16x128, unit scales = exact fp8) + exp(sim/2) + row-sum.
// R11: PERSISTENT blocks + cross-tile B double-buffer. Evidence: four
// single-shot variants (R0/R1/R3/R4) all plateau at 36-43us while R1's
// counters show per-block pipes near ideal -> the shared cost is the stage
// stall serialized with compute at ~1 block/CU, paid 4-16x serially per CU.
// Now: grid = 256 blocks exactly (1/CU, 8 waves). Block owns a 256-row A
// panel (staged ONCE, 64KB) and walks 8 col-tiles of 128 nv-rows with B
// double-buffered (2x32KB): B(t+1) always in flight under compute(t) via
// counted vmcnt (stores stay younger: vmcnt(1) retires exactly the 4 B
// loads). Stage latency paid once, not per tile. Traffic: A 1x + B 1x =
// 82MB (vs 268MB at 128^2 tiling); cg=bid&7 puts one 256KB B col-group +
// 2MB A per XCD -> L2-resident. Wave tile 64x64 (acc 4x4 = 64 VGPR, 2
// waves/SIMD). Fragment decode / swizzle / swapped MFMA / epilogue order
// identical to R4 (absmax 0) -> numerics unchanged.
__global__ __launch_bounds__(512, 2) void gemm_lse_kernel(
    const unsigned char* __restrict__ gA, const unsigned char* __restrict__ gB,
    float* __restrict__ partial, int N) {
  __shared__ unsigned char As[65536];     // [2 kb][256 rows][8 chunks 16B, swz]
  __shared__ unsigned char Bs[2][32768];  // per buf: [2 kb][128 rows][8 chunks]

  const int tid  = threadIdx.x;
  const int lane = tid & 63;
  const int wv   = tid >> 6;      // 0..7
  const int wm   = wv >> 1;       // 0..3 : 64-row strip of the 256-row panel
  const int wn   = wv & 1;        // 0..1 : 64-col half of the 128-col tile
  const int l15  = lane & 15, q = lane >> 4;
  const int cg    = blockIdx.x;   // 0..7  : 1024-col group (fixed per XCD)
  const int panel = blockIdx.y;   // 0..31 : 256-row panel
  const int row0  = panel * 256;
  const int colBase = cg * 1024;
  const float kLog2eHalf = 0.72134752044448170f;  // log2(e)/2
  const int kUnitScale = 0x7F7F7F7F;              // e8m0 127 = 2^0 per byte

  auto stageB = [&](int t) {
    const unsigned char* src = gB + (size_t)(colBase + t * 128) * 256;
    unsigned char* dst = &Bs[t & 1][0];
#pragma unroll
    for (int kb = 0; kb < 2; kb++)
#pragma unroll
      for (int i = 0; i < 2; i++) {
        int c  = i * 512 + tid;            // chunk within this kb-half
        int r  = c >> 3;                   // 0..127
        int sc = ((c & 7) ^ (r & 7)) << 4; // pre-swizzled global source col
        GLD_LDS16(src + (size_t)r * 256 + kb * 128 + sc,
                  dst + kb * 16384 + c * 16);
      }
  };

  // Prologue: stage A panel (8 loads/thread) + B0 + B1 (4 each).
#pragma unroll
  for (int kb = 0; kb < 2; kb++)
#pragma unroll
    for (int i = 0; i < 4; i++) {
      int c  = i * 512 + tid;
      int r  = c >> 3;                     // 0..255
      int sc = ((c & 7) ^ (r & 7)) << 4;
      GLD_LDS16(gA + (size_t)(row0 + r) * 256 + kb * 128 + sc,
                As + kb * 32768 + c * 16);
    }
  stageB(0);
  stageB(1);
  // retire A+B0 (12 oldest of 16); B1's 4 stay in flight under tile 0.
  asm volatile("s_waitcnt vmcnt(4)\n\ts_barrier" ::: "memory");

#pragma unroll 2
  for (int t = 0; t < 8; t++) {
    if (t) {
      // in flight: B(t)'s 4 loads (oldest) + 1 store from tile t-1.
      // vmcnt(1) retires exactly the B loads; the store drains later.
      asm volatile("s_waitcnt vmcnt(1)\n\ts_barrier" ::: "memory");
      if (t < 7) stageB(t + 1);   // into buf[(t+1)&1]; safe: all waves past
    }                             // the barrier after computing t-1.
    const unsigned char* bufB = &Bs[t & 1][0];

    f32x4 acc[4][4];
#pragma unroll
    for (int mi = 0; mi < 4; mi++)
#pragma unroll
      for (int ni = 0; ni < 4; ni++) acc[mi][ni] = (f32x4){0.f, 0.f, 0.f, 0.f};

#pragma unroll
    for (int kb = 0; kb < 2; kb++) {
      i32x8 bf[4];
#pragma unroll
      for (int ni = 0; ni < 4; ni++) {
        int r  = wn * 64 + ni * 16 + l15;           // 0..127
        int c0 = (q * 2)     ^ (r & 7);
        int c1 = (q * 2 + 1) ^ (r & 7);
        i32x4 lo = *(const i32x4*)(bufB + kb * 16384 + r * 128 + c0 * 16);
        i32x4 hi = *(const i32x4*)(bufB + kb * 16384 + r * 128 + c1 * 16);
        bf[ni] = (i32x8){lo.x, lo.y, lo.z, lo.w, hi.x, hi.y, hi.z, hi.w};
      }
#pragma unroll
      for (int mi = 0; mi < 4; mi++) {
        int r  = wm * 64 + mi * 16 + l15;           // 0..255
        int c0 = (q * 2)     ^ (r & 7);
        int c1 = (q * 2 + 1) ^ (r & 7);
        i32x4 lo = *(const i32x4*)(As + kb * 32768 + r * 128 + c0 * 16);
        i32x4 hi = *(const i32x4*)(As + kb * 32768 + r * 128 + c1 * 16);
        i32x8 af = (i32x8){lo.x, lo.y, lo.z, lo.w, hi.x, hi.y, hi.z, hi.w};
        __builtin_amdgcn_s_setprio(1);
#pragma unroll
        for (int ni = 0; ni < 4; ni++)
          acc[mi][ni] = __builtin_amdgcn_mfma_scale_f32_16x16x128_f8f6f4(
              bf[ni], af, acc[mi][ni],        // SWAPPED: D[col][row]
              0, 0, 0, kUnitScale, 0, kUnitScale);
        __builtin_amdgcn_s_setprio(0);
      }
    }

    // epilogue (R4-verified): lane l15 = pk-row within 16; regs span nv-cols.
    // Row-sum over the wave's 64 cols = in-register + 2 cross-q shuffles.
    float s0, s1, s2, s3;
#pragma unroll
    for (int mi = 0; mi < 4; mi++) {
      float v = 0.f;
#pragma unroll
      for (int ni = 0; ni < 4; ni++)
#pragma unroll
        for (int rr = 0; rr < 4; rr++)
          v += __builtin_amdgcn_exp2f(acc[mi][ni][rr] * kLog2eHalf);
      v += __shfl_xor(v, 16, 64);
      v += __shfl_xor(v, 32, 64);
      if (mi == 0) s0 = v; else if (mi == 1) s1 = v;
      else if (mi == 2) s2 = v; else s3 = v;
    }
    // lane (q,l15) stores row wm*64 + q*16 + l15 (mi = q): one coalesced
    // 256B store per wave per tile.
    float o = q == 0 ? s0 : q == 1 ? s1 : q == 2 ? s2 : s3;
    int slab = cg * 16 + t * 2 + wn;                // 64-col slab, 0..127
    partial[(size_t)slab * N + row0 + wm * 64 + q * 16 + l15] = o;
  }
}

// out = mean(ln(sum_j partial[j][row])) - 0.5*mean(posPart). UNCHANGED
// (partial is still [M/64=128][N]).
__global__ __launch_bounds__(256) void finalize_kernel(
    const float* __restrict__ partial, const float* __restrict__ posPart,
    float* __restrict__ out, int N, int slabsPerGroup, float invN) {
  __shared__ float red[4][64];
  int t  = threadIdx.x;
  int rl = t & 63, g = t >> 6;
  int row = blockIdx.x * 64 + rl;
  const float* p = partial + (size_t)(g * slabsPerGroup) * N + row;
  float s = 0.f;
#pragma unroll 8
  for (int j = 0; j < slabsPerGroup; j++) s += p[(size_t)j * N];
  red[g][rl] = s;
  __syncthreads();
  if (t < 64) {
    float tot = red[0][rl] + red[1][rl] + red[2][rl] + red[3][rl];
    float v = __builtin_amdgcn_logf(tot) * 0.69314718055994531f
              - 0.5f * posPart[row];
#pragma unroll
    for (int m = 32; m >= 1; m >>= 1) v += __shfl_xor(v, m, 64);
    if (rl == 0) atomicAdd(out, v * invN);
  }
}

extern "C" void kernel_launch(void* const* d_in, const int* in_sizes, int n_in,
                              void* d_out, int out_size, void* d_ws, size_t ws_size,
                              hipStream_t stream) {
  const float* pk = (const float*)d_in[0];
  const float* pv = (const float*)d_in[1];
  const float* nv = (const float*)d_in[2];
  int N = in_sizes[0] / DIM;   // 8192
  int M = in_sizes[2] / DIM;   // 8192
  float* out = (float*)d_out;

  unsigned char* pkn = (unsigned char*)d_ws;                   // [N,256] fp8
  unsigned char* nvn = pkn + (size_t)N * DIM;                  // [M,256] fp8
  float* partial = (float*)(nvn + (size_t)M * DIM);            // [M/64][N] fp32
  float* posPart = partial + (size_t)(M / 64) * N;             // [N] fp32

  hipMemsetAsync(out, 0, sizeof(float), stream);

  normalize_kernel<<<(N + M) / 4, 256, 0, stream>>>(
      (const float4*)pk, (const float4*)pv, (const float4*)nv,
      (unsigned int*)pkn, (unsigned int*)nvn, posPart, N);

  // grid: x = col-group (M/1024 = 8, one per XCD slot), y = row panel (32).
  gemm_lse_kernel<<<dim3(M / 1024, N / 256), 512, 0, stream>>>(
      pkn, nvn, partial, N);

  finalize_kernel<<<N / 64, 256, 0, stream>>>(
      partial, posPart, out, N, (M / 64) / 4, 1.0f / (float)N);
}

// Round 6
// 101.038 us; speedup vs baseline: 1.3500x; 1.0001x over previous
//
#include <hip/hip_runtime.h>

typedef __attribute__((ext_vector_type(4))) float f32x4;
typedef __attribute__((ext_vector_type(4))) int   i32x4;
typedef __attribute__((ext_vector_type(8))) int   i32x8;

#define DIM 256
#define D4  64    // float4 per row

// async global->LDS, 16B per lane; LDS dest = wave-uniform base + lane*16.
#define GLD_LDS16(g, l) __builtin_amdgcn_global_load_lds(                      \
    (const __attribute__((address_space(1))) void*)(g),                        \
    (__attribute__((address_space(3))) void*)(l), 16, 0, 0)

// wait for all but the newest N VMEM ops, then barrier (counted prefetch).
#define TILE_WAIT(N) asm volatile("s_waitcnt vmcnt(" #N ")\n\ts_barrier" ::: "memory")

// One wave per row. Rows [0,N): exact fp32 pos_sim -> posPart[row] + normalized
// pk -> fp8 e4m3 (plain byte-k order). Rows [N,N+M): normalized nv -> fp8.
// UNCHANGED (near its HBM floor).
__global__ __launch_bounds__(256) void normalize_kernel(
    const float4* __restrict__ pk, const float4* __restrict__ pv,
    const float4* __restrict__ nv, unsigned int* __restrict__ pkn,
    unsigned int* __restrict__ nvn, float* __restrict__ posPart, int N) {
  int row  = blockIdx.x * 4 + (threadIdx.x >> 6);
  int lane = threadIdx.x & 63;
  if (row < N) {
    float4 x = pk[row * D4 + lane];
    float4 y = pv[row * D4 + lane];
    float skk = x.x*x.x + x.y*x.y + x.z*x.z + x.w*x.w;
    float svv = y.x*y.x + y.y*y.y + y.z*y.z + y.w*y.w;
    float skv = x.x*y.x + x.y*y.y + x.z*y.z + x.w*y.w;
#pragma unroll
    for (int m = 32; m >= 1; m >>= 1) {
      skk += __shfl_xor(skk, m, 64);
      svv += __shfl_xor(svv, m, 64);
      skv += __shfl_xor(skv, m, 64);
    }
    float nk  = fmaxf(sqrtf(skk), 1e-8f);
    float nvv = fmaxf(sqrtf(svv), 1e-8f);
    if (lane == 0) posPart[row] = skv / (nk * nvv);
    float rk = 1.0f / nk;
    int w = __builtin_amdgcn_cvt_pk_fp8_f32(x.x * rk, x.y * rk, 0, false);
    w = __builtin_amdgcn_cvt_pk_fp8_f32(x.z * rk, x.w * rk, w, true);
    pkn[(size_t)row * 64 + lane] = (unsigned int)w;
  } else {
    int r2 = row - N;
    float4 x = nv[r2 * D4 + lane];
    float s = x.x*x.x + x.y*x.y + x.z*x.z + x.w*x.w;
#pragma unroll
    for (int m = 32; m >= 1; m >>= 1) s += __shfl_xor(s, m, 64);
    float rn = 1.0f / fmaxf(sqrtf(s), 1e-8f);
    int w = __builtin_amdgcn_cvt_pk_fp8_f32(x.x * rn, x.y * rn, 0, false);
    w = __builtin_amdgcn_cvt_pk_fp8_f32(x.z * rn, x.w * rn, w, true);
    nvn[(size_t)r2 * 64 + lane] = (unsigned int)w;
  }
}

// Fused fp8 GEMM (MX 16x16x128, unit scales = exact fp8) + exp(sim/2) + row-sum.
// R12: A-IN-REGISTERS. Evidence: all 5 prior variants re-read A+B from LDS
// every tile -> 256KB/tile/CU through the 128B/cy LDS pipe (~2.4-3k cy) >=
// MFMA time (2.2k cy); LDS was the co-bottleneck the barrier work couldn't
// expose. A panel is FIXED per persistent block -> hold it in regs: af[2][4]
// = 64 VGPR/wave, loaded ONCE direct from L2 (R2-verified addressing; R2's
// failure was re-loading per tile). Per tile only B ds_reads (16 b128/wave):
// LDS traffic 2.4MB -> 1.2MB per block. B: 4-deep LDS buffers (128KB, freed
// by evicting A), staged 3 tiles ahead, exact counted vmcnt per tile
// (per-thread VMEM issue order: stage=4 loads, store=1; minus-1 safety),
// sched_barrier(0) pins issue order. Fragment bytes / MFMA operand order /
// accumulation order / epilogue / partial layout identical to R5 -> absmax 0.
__global__ __launch_bounds__(512, 2) void gemm_lse_kernel(
    const unsigned char* __restrict__ gA, const unsigned char* __restrict__ gB,
    float* __restrict__ partial, int N) {
  __shared__ unsigned char Bs[4][32768];  // per buf: [2 kb][128 rows][8 chunks]

  const int tid  = threadIdx.x;
  const int lane = tid & 63;
  const int wv   = tid >> 6;      // 0..7
  const int wm   = wv >> 1;       // 0..3 : 64-row strip of the 256-row panel
  const int wn   = wv & 1;        // 0..1 : 64-col half of the 128-col tile
  const int l15  = lane & 15, q = lane >> 4;
  const int cg    = blockIdx.x;   // 0..7  : 1024-col group (fixed per XCD)
  const int panel = blockIdx.y;   // 0..31 : 256-row panel
  const int row0  = panel * 256;
  const int colBase = cg * 1024;
  const float kLog2eHalf = 0.72134752044448170f;  // log2(e)/2
  const int kUnitScale = 0x7F7F7F7F;              // e8m0 127 = 2^0 per byte

  auto stageB = [&](int t) {
    const unsigned char* src = gB + (size_t)(colBase + t * 128) * 256;
    unsigned char* dst = &Bs[t & 3][0];
#pragma unroll
    for (int kb = 0; kb < 2; kb++)
#pragma unroll
      for (int i = 0; i < 2; i++) {
        int c  = i * 512 + tid;            // chunk within this kb-half
        int r  = c >> 3;                   // 0..127
        int sc = ((c & 7) ^ (r & 7)) << 4; // pre-swizzled global source col
        GLD_LDS16(src + (size_t)r * 256 + kb * 128 + sc,
                  dst + kb * 16384 + c * 16);
      }
  };

  // A fragments straight to registers, once (16 dwordx4 per thread).
  // Row = row0 + wm*64 + mi*16 + l15; K-bytes kb*128 + q*32 .. +31.
  const unsigned char* aB = gA + (size_t)(row0 + wm * 64 + l15) * 256 + q * 32;
  i32x8 af[2][4];
#pragma unroll
  for (int kb = 0; kb < 2; kb++)
#pragma unroll
    for (int mi = 0; mi < 4; mi++)
      af[kb][mi] = *(const i32x8*)(aB + mi * 16 * 256 + kb * 128);
  __builtin_amdgcn_sched_barrier(0);   // pin: A loads issue before B stages

  stageB(0);
  stageB(1);
  stageB(2);
  __builtin_amdgcn_sched_barrier(0);

#pragma unroll
  for (int t = 0; t < 8; t++) {
    // Counted waits (per-thread VMEM age math, exact minus 1 for safety):
    // guarantee B(t) fully in LDS while keeping 2-3 stage-groups in flight.
    if      (t == 0) TILE_WAIT(7);
    else if (t == 1) TILE_WAIT(8);
    else if (t == 2) TILE_WAIT(9);
    else if (t == 3) TILE_WAIT(10);
    else if (t == 4) TILE_WAIT(10);
    else if (t == 5) TILE_WAIT(10);
    else if (t == 6) TILE_WAIT(6);
    else             TILE_WAIT(2);

    if (t < 5) {                 // stage B(t+3) into buf[(t+3)&3]: that buf
      stageB(t + 3);             // held B(t-1), consumed before this barrier.
      __builtin_amdgcn_sched_barrier(0);
    }

    const unsigned char* bufB = &Bs[t & 3][0];
    f32x4 acc[4][4];
#pragma unroll
    for (int mi = 0; mi < 4; mi++)
#pragma unroll
      for (int ni = 0; ni < 4; ni++) acc[mi][ni] = (f32x4){0.f, 0.f, 0.f, 0.f};

#pragma unroll
    for (int kb = 0; kb < 2; kb++) {
      i32x8 bf[4];
#pragma unroll
      for (int ni = 0; ni < 4; ni++) {
        int r  = wn * 64 + ni * 16 + l15;           // 0..127
        int c0 = (q * 2)     ^ (r & 7);
        int c1 = (q * 2 + 1) ^ (r & 7);
        i32x4 lo = *(const i32x4*)(bufB + kb * 16384 + r * 128 + c0 * 16);
        i32x4 hi = *(const i32x4*)(bufB + kb * 16384 + r * 128 + c1 * 16);
        bf[ni] = (i32x8){lo.x, lo.y, lo.z, lo.w, hi.x, hi.y, hi.z, hi.w};
      }
#pragma unroll
      for (int mi = 0; mi < 4; mi++) {
        __builtin_amdgcn_s_setprio(1);
#pragma unroll
        for (int ni = 0; ni < 4; ni++)
          acc[mi][ni] = __builtin_amdgcn_mfma_scale_f32_16x16x128_f8f6f4(
              bf[ni], af[kb][mi], acc[mi][ni],    // SWAPPED: D[col][row]
              0, 0, 0, kUnitScale, 0, kUnitScale);
        __builtin_amdgcn_s_setprio(0);
      }
    }

    // epilogue (R4/R5-verified): lane l15 = pk-row within 16; regs span
    // nv-cols. Row-sum over the wave's 64 cols = in-register + 2 shuffles.
    float s0, s1, s2, s3;
#pragma unroll
    for (int mi = 0; mi < 4; mi++) {
      float v = 0.f;
#pragma unroll
      for (int ni = 0; ni < 4; ni++)
#pragma unroll
        for (int rr = 0; rr < 4; rr++)
          v += __builtin_amdgcn_exp2f(acc[mi][ni][rr] * kLog2eHalf);
      v += __shfl_xor(v, 16, 64);
      v += __shfl_xor(v, 32, 64);
      if (mi == 0) s0 = v; else if (mi == 1) s1 = v;
      else if (mi == 2) s2 = v; else s3 = v;
    }
    float o = q == 0 ? s0 : q == 1 ? s1 : q == 2 ? s2 : s3;
    int slab = cg * 16 + t * 2 + wn;                // 64-col slab, 0..127
    partial[(size_t)slab * N + row0 + wm * 64 + q * 16 + l15] = o;
    __builtin_amdgcn_sched_barrier(0);   // pin: store issues before next stage
  }
}

// out = mean(ln(sum_j partial[j][row])) - 0.5*mean(posPart). UNCHANGED
// (partial is still [M/64=128][N]).
__global__ __launch_bounds__(256) void finalize_kernel(
    const float* __restrict__ partial, const float* __restrict__ posPart,
    float* __restrict__ out, int N, int slabsPerGroup, float invN) {
  __shared__ float red[4][64];
  int t  = threadIdx.x;
  int rl = t & 63, g = t >> 6;
  int row = blockIdx.x * 64 + rl;
  const float* p = partial + (size_t)(g * slabsPerGroup) * N + row;
  float s = 0.f;
#pragma unroll 8
  for (int j = 0; j < slabsPerGroup; j++) s += p[(size_t)j * N];
  red[g][rl] = s;
  __syncthreads();
  if (t < 64) {
    float tot = red[0][rl] + red[1][rl] + red[2][rl] + red[3][rl];
    float v = __builtin_amdgcn_logf(tot) * 0.69314718055994531f
              - 0.5f * posPart[row];
#pragma unroll
    for (int m = 32; m >= 1; m >>= 1) v += __shfl_xor(v, m, 64);
    if (rl == 0) atomicAdd(out, v * invN);
  }
}

extern "C" void kernel_launch(void* const* d_in, const int* in_sizes, int n_in,
                              void* d_out, int out_size, void* d_ws, size_t ws_size,
                              hipStream_t stream) {
  const float* pk = (const float*)d_in[0];
  const float* pv = (const float*)d_in[1];
  const float* nv = (const float*)d_in[2];
  int N = in_sizes[0] / DIM;   // 8192
  int M = in_sizes[2] / DIM;   // 8192
  float* out = (float*)d_out;

  unsigned char* pkn = (unsigned char*)d_ws;                   // [N,256] fp8
  unsigned char* nvn = pkn + (size_t)N * DIM;                  // [M,256] fp8
  float* partial = (float*)(nvn + (size_t)M * DIM);            // [M/64][N] fp32
  float* posPart = partial + (size_t)(M / 64) * N;             // [N] fp32

  hipMemsetAsync(out, 0, sizeof(float), stream);

  normalize_kernel<<<(N + M) / 4, 256, 0, stream>>>(
      (const float4*)pk, (const float4*)pv, (const float4*)nv,
      (unsigned int*)pkn, (unsigned int*)nvn, posPart, N);

  // grid: x = col-group (M/1024 = 8, one per XCD slot), y = row panel (32).
  gemm_lse_kernel<<<dim3(M / 1024, N / 256), 512, 0, stream>>>(
      pkn, nvn, partial, N);

  finalize_kernel<<<N / 64, 256, 0, stream>>>(
      partial, posPart, out, N, (M / 64) / 4, 1.0f / (float)N);
}